// Round 4
// baseline (252.284 us; speedup 1.0000x reference)
//
#include <hip/hip_runtime.h>

// ---- problem constants ----
#define Bq   4
#define Sq   2048
#define Eq   1024
#define Hq   16
#define HDq  64
#define Mq   (Bq*Sq)       // 8192
#define N1q  (3*Eq)        // 3072
#define Kq   Eq            // 1024

#define NX4  (Mq*Kq/4)     // x float4 count        2097152
#define NW4  (N1q*Kq/4)    // w_qkv float4 count     786432
#define NP4  (Eq*Kq/4)     // w_proj float4 count    262144

typedef __bf16 bf16x8 __attribute__((ext_vector_type(8)));
typedef __bf16 bf16x4 __attribute__((ext_vector_type(4)));
typedef float  f32x4  __attribute__((ext_vector_type(4)));
typedef float  f32x16 __attribute__((ext_vector_type(16)));

#define GAS __attribute__((address_space(1)))
#define LAS __attribute__((address_space(3)))

__device__ __forceinline__ void gl2lds16(const void* g, void* l) {
  __builtin_amdgcn_global_load_lds((GAS const void*)g, (LAS void*)l, 16, 0, 0);
}

__device__ __forceinline__ unsigned pack2(float a, float b) {
  union { __bf16 h[2]; unsigned u; } x;
  x.h[0] = (__bf16)a; x.h[1] = (__bf16)b; return x.u;
}

// v_permlane32_swap_b32: a' = [a.lo32, b.lo32], b' = [a.hi32, b.hi32]
// (VALU lane-swap; replaced ds_bpermute __shfl_xor which cost 8 LDS-conflict
// cycles each — r2's entire 4.46M SQ_LDS_BANK_CONFLICT. r3: confirmed win.)
__device__ __forceinline__ void perm32swap(unsigned& a, unsigned& b) {
  asm("v_permlane32_swap_b32 %0, %1" : "+v"(a), "+v"(b));
}

// raw v_exp_f32 (args here are always <= -6 or -1e30: no denorm-fixup needed)
__device__ __forceinline__ float fexp2(float x) {
#if __has_builtin(__builtin_amdgcn_exp2f)
  return __builtin_amdgcn_exp2f(x);
#else
  return exp2f(x);
#endif
}

// ---- single fused fp32->bf16 convert for all three inputs --------------
// w_qkv Q-rows (row%192 < 64) get HD^-0.5*log2(e) folded in so attention
// scores exit MFMA already in base-2 domain.
__global__ __launch_bounds__(256) void cvt_all(const float* __restrict__ x,
                                               const float* __restrict__ wqkv,
                                               const float* __restrict__ wproj,
                                               __bf16* __restrict__ xb,
                                               __bf16* __restrict__ wqkvb,
                                               __bf16* __restrict__ wprojb) {
  int i = blockIdx.x * 256 + threadIdx.x;
  const float* src; __bf16* dst; int j; float sc = 1.0f;
  if (i < NX4) {
    src = x; dst = xb; j = i;
  } else if (i < NX4 + NW4) {
    j = i - NX4; src = wqkv; dst = wqkvb;
    const int row = j >> 8;                    // K=1024 -> 256 float4/row
    if ((row % 192) < 64) sc = 0.18033688011112042f;
  } else {
    j = i - NX4 - NW4; src = wproj; dst = wprojb;
  }
  float4 v = ((const float4*)src)[j];
  bf16x4 o = { (__bf16)(v.x * sc), (__bf16)(v.y * sc),
               (__bf16)(v.z * sc), (__bf16)(v.w * sc) };
  ((bf16x4*)dst)[j] = o;
}

// ---------------- GEMM  C = A(MxK) * B(NxK)^T  (both K-major, bf16) ------
// 128x128 tile, BK=64 (two 32-wide kk-halves per sync). LDS 32 KiB
// single-buffered. LDS chunk-XOR swizzle (proven 0 bank conflicts).
template <int MODE>
__global__ __launch_bounds__(256) void gemm_bt(const __bf16* __restrict__ A,
                                               const __bf16* __restrict__ Bw,
                                               int N, int K,
                                               __bf16* __restrict__ cbf,
                                               const float* __restrict__ bias,
                                               float* __restrict__ cf32) {
  __shared__ __align__(16) __bf16 As[128 * 64];   // [kk][128][32], 16 KiB
  __shared__ __align__(16) __bf16 Bs[128 * 64];
  const int tid  = threadIdx.x;
  const int wave = tid >> 6, lane = tid & 63;
  const int quad = lane >> 4, l15 = lane & 15;
  const int wm = wave & 1, wn = wave >> 1;
  const int bm0 = blockIdx.x * 128;
  const int bn0 = blockIdx.y * 128;

  f32x4 acc[4][4] = {};

  const int ar = tid >> 2;
  const int ac = ((tid & 3) ^ ((tid >> 3) & 3)) * 8;   // swizzled global chunk
  const __bf16* Ag0 = A  + (long)(bm0 + ar) * K + ac;
  const __bf16* Bg0 = Bw + (long)(bn0 + ar) * K + ac;
  // region bases: +0 rows 0-63 kk0, +2048 rows 64-127 kk0,
  //               +4096 rows 0-63 kk1, +6144 rows 64-127 kk1
  __bf16* As0 = As + wave * 512;
  __bf16* Bs0 = Bs + wave * 512;

  const int fsw = (l15 >> 1) & 3;                      // fragment-read swizzle
  const int a_rd = (wm * 64 + l15) * 32 + (quad ^ fsw) * 8;
  const int b_rd = (wn * 64 + l15) * 32 + (quad ^ fsw) * 8;

  for (int kc = 0; kc < K; kc += 64) {
    gl2lds16(Ag0 + kc,               As0);
    gl2lds16(Ag0 + 64 * K + kc,      As0 + 2048);
    gl2lds16(Ag0 + kc + 32,          As0 + 4096);
    gl2lds16(Ag0 + 64 * K + kc + 32, As0 + 6144);
    gl2lds16(Bg0 + kc,               Bs0);
    gl2lds16(Bg0 + 64 * K + kc,      Bs0 + 2048);
    gl2lds16(Bg0 + kc + 32,          Bs0 + 4096);
    gl2lds16(Bg0 + 64 * K + kc + 32, Bs0 + 6144);
    __syncthreads();

    bf16x8 af[4], bfr[4];
    // ---- kk0 (K 0..31 of this step) ----
#pragma unroll
    for (int mt = 0; mt < 4; mt++)
      af[mt] = *(const bf16x8*)&As[a_rd + mt * 512];
#pragma unroll
    for (int nt = 0; nt < 4; nt++)
      bfr[nt] = *(const bf16x8*)&Bs[b_rd + nt * 512];
#pragma unroll
    for (int mt = 0; mt < 4; mt++)
#pragma unroll
      for (int nt = 0; nt < 4; nt++)
        acc[mt][nt] = __builtin_amdgcn_mfma_f32_16x16x32_bf16(af[mt], bfr[nt], acc[mt][nt], 0, 0, 0);

    // ---- kk1 (K 32..63 of this step) ----
    bf16x8 af1[4], bfr1[4];
#pragma unroll
    for (int mt = 0; mt < 4; mt++)
      af1[mt] = *(const bf16x8*)&As[4096 + a_rd + mt * 512];
#pragma unroll
    for (int nt = 0; nt < 4; nt++)
      bfr1[nt] = *(const bf16x8*)&Bs[4096 + b_rd + nt * 512];
#pragma unroll
    for (int mt = 0; mt < 4; mt++)
#pragma unroll
      for (int nt = 0; nt < 4; nt++)
        acc[mt][nt] = __builtin_amdgcn_mfma_f32_16x16x32_bf16(af1[mt], bfr1[nt], acc[mt][nt], 0, 0, 0);
    __syncthreads();
  }

#pragma unroll
  for (int nt = 0; nt < 4; nt++) {
    const int n = bn0 + wn * 64 + nt * 16 + l15;
    float bv = 0.f;
    if (MODE == 1) bv = bias[n];
#pragma unroll
    for (int mt = 0; mt < 4; mt++) {
      const int mbase = bm0 + wm * 64 + mt * 16 + quad * 4;
#pragma unroll
      for (int r = 0; r < 4; r++) {
        const long m = mbase + r;
        if (MODE == 0) cbf[m * N + n] = (__bf16)acc[mt][nt][r];
        else           cf32[m * N + n] = acc[mt][nt][r] + bv;
      }
    }
  }
}

// ---------------- V transpose: qkv natural layout -> vt[bh][d][s] --------
__global__ __launch_bounds__(256) void transv(const __bf16* __restrict__ qkv,
                                              __bf16* __restrict__ vt) {
  __shared__ __align__(16) __bf16 T[64 * 64];
  const int tid = threadIdx.x, wave = tid >> 6;
  const int bh = blockIdx.x >> 5, st = blockIdx.x & 31;
  const int b = bh >> 4, h = bh & 15;
  const long gbase = (long)(b * Sq + st * 64 + (tid >> 3)) * N1q + h * 192 + 128 + (tid & 7) * 8;
  gl2lds16(qkv + gbase,                  T + wave * 512);
  gl2lds16(qkv + gbase + (long)32 * N1q, T + 2048 + wave * 512);
  __syncthreads();
  const int d = tid >> 2, s4 = (tid & 3) * 16;
  bf16x8 o0, o1;
#pragma unroll
  for (int j = 0; j < 8; j++) o0[j] = T[(s4 + j) * 64 + d];
#pragma unroll
  for (int j = 0; j < 8; j++) o1[j] = T[(s4 + 8 + j) * 64 + d];
  __bf16* dst = vt + (long)(bh * 64 + d) * Sq + st * 64 + s4;
  *(bf16x8*)dst = o0;
  *(bf16x8*)(dst + 8) = o1;
}

// ---------------- flash attention fwd (causal), transposed-scores --------
// Grid 1024, blockIdx = j*256 + k*64 + bh; qt = 4*j + ((k+j)&3) (Latin
// square: per-CU-slot work uniform). Fixed-max base-2 softmax (scale folded
// into w_qkv cvt; -MB folded into MFMA C-init). Per-nf fusion keeps one
// f32x16 of scores live.
//
// r4: K/V double-buffered in FOUR STATIC LDS arrays (Ks0/Ks1/Vs0/Vs1),
// kt-loop unrolled x2 so stage(kt+1) ds-writes provably never alias
// compute(kt) ds-reads -> no compiler vmcnt-drain between stage-issue and
// compute. One __syncthreads per tile (was 2). r3 counters (per-CU):
// MfmaUtil 21% + VALUBusy 44% => ~85% of time was staging-latency stall.
// launch_bounds(256,2): do NOT tighten (old r4: (256,4) forced spills).
__global__ __launch_bounds__(256, 2) void attn_fwd(const __bf16* __restrict__ qkv,
                                                   const __bf16* __restrict__ vt,
                                                   __bf16* __restrict__ aout) {
  __shared__ __align__(16) __bf16 Ks0[128 * 64];  // [kcol][d], XOR-swizzled
  __shared__ __align__(16) __bf16 Ks1[128 * 64];
  __shared__ __align__(16) __bf16 Vs0[64 * 128];  // [d][kcol], XOR-swizzled
  __shared__ __align__(16) __bf16 Vs1[64 * 128];

  const int tid = threadIdx.x;
  const int w = tid >> 6, lane = tid & 63;
  const int c = lane & 31, h = lane >> 5;
  const int bi = blockIdx.x;
  const int bh = bi & 63, kk = (bi >> 6) & 3, jr = bi >> 8;
  const int qt = 4 * jr + ((kk + jr) & 3);
  const int b = bh >> 4, head = bh & 15;

  const int krr = lane >> 3, kj = lane & 7;
  const int vrr = lane >> 4, vj = lane & 15;

  const int q_g = qt * 128 + w * 32 + c;

  bf16x8 qf[4];
  const __bf16* qp = qkv + (long)(b * Sq + q_g) * N1q + head * 192 + h * 8;
#pragma unroll
  for (int kc2 = 0; kc2 < 4; kc2++) qf[kc2] = *(const bf16x8*)(qp + kc2 * 16);

  f32x16 oT[2] = {};
  float l_i = 0.f;
  constexpr float MB = 16.0f;   // fixed softmax max (base-2 domain)

#define ATTN_STAGE(KD, VD, kt_) do {                                          \
    _Pragma("unroll")                                                         \
    for (int i = 0; i < 4; i++) {                                             \
      const int row = w * 32 + i * 8 + krr;                                   \
      gl2lds16(qkv + (long)(b * Sq + (kt_) * 128 + row) * N1q + head * 192    \
                   + 64 + (kj ^ (krr & 7)) * 8,                               \
               (KD) + (w * 32 + i * 8) * 64);                                 \
    }                                                                         \
    _Pragma("unroll")                                                         \
    for (int i = 0; i < 4; i++) {                                             \
      const int dr = w * 16 + i * 4 + vrr;                                    \
      gl2lds16(vt + (long)(bh * 64 + dr) * Sq + (kt_) * 128                   \
                  + (vj ^ (dr & 7)) * 8,                                      \
               (VD) + (w * 16 + i * 4) * 128);                                \
    }                                                                         \
  } while (0)

#define ATTN_COMPUTE(KS, VS, kt_) do {                                        \
    const bool diag = ((kt_) == qt);                                          \
    float s_acc = 0.f;                                                        \
    _Pragma("unroll")                                                         \
    for (int nf = 0; nf < 4; nf++) {                                          \
      f32x16 z;                                                               \
      _Pragma("unroll")                                                       \
      for (int r = 0; r < 16; r++) z[r] = -MB;  /* C-init = -MB: no v_sub */  \
      _Pragma("unroll")                                                       \
      for (int kc2 = 0; kc2 < 4; kc2++) {                                     \
        bf16x8 kf = *(const bf16x8*)&(KS)[(nf * 32 + c) * 64                  \
                                          + (((kc2 * 2 + h) ^ (c & 7)) * 8)]; \
        z = __builtin_amdgcn_mfma_f32_32x32x16_bf16(kf, qf[kc2], z, 0, 0, 0); \
      }                                                                       \
      if (diag) {                                                             \
        _Pragma("unroll")                                                     \
        for (int r = 0; r < 16; r++) {                                        \
          const int kcol = (kt_) * 128 + nf * 32 + (r & 3) + 8 * (r >> 2)     \
                           + 4 * h;                                           \
          if (kcol > q_g) z[r] = -1e30f;                                      \
        }                                                                     \
      }                                                                       \
      _Pragma("unroll")                                                       \
      for (int r = 0; r < 16; r++) {                                          \
        float p = fexp2(z[r]);                                                \
        z[r] = p; s_acc += p;                                                 \
      }                                                                       \
      _Pragma("unroll")                                                       \
      for (int sub = 0; sub < 2; sub++) {                                     \
        const int kc = nf * 2 + sub, base = 8 * sub;                          \
        unsigned pa0 = pack2(z[base + 0], z[base + 1]);                       \
        unsigned pa1 = pack2(z[base + 2], z[base + 3]);                       \
        unsigned pb0 = pack2(z[base + 4], z[base + 5]);                       \
        unsigned pb1 = pack2(z[base + 6], z[base + 7]);                       \
        perm32swap(pa0, pb0);                                                 \
        perm32swap(pa1, pb1);                                                 \
        union { bf16x8 v; unsigned u[4]; } pf;                                \
        pf.u[0] = pa0; pf.u[1] = pa1; pf.u[2] = pb0; pf.u[3] = pb1;           \
        _Pragma("unroll")                                                     \
        for (int nf2 = 0; nf2 < 2; nf2++) {                                   \
          bf16x8 vf = *(const bf16x8*)&(VS)[(nf2 * 32 + c) * 128              \
                                            + (((kc * 2 + h) ^ (c & 7)) * 8)];\
          oT[nf2] = __builtin_amdgcn_mfma_f32_32x32x16_bf16(vf, pf.v,         \
                                                            oT[nf2], 0, 0, 0);\
        }                                                                     \
      }                                                                       \
    }                                                                         \
    l_i += s_acc;                                                             \
  } while (0)

  const int nk = qt + 1;
  ATTN_STAGE(Ks0, Vs0, 0);
  __syncthreads();

  int kt = 0;
  for (; kt + 1 < nk; kt += 2) {
    // tile kt (buffers 0); prefetch kt+1 into buffers 1
    ATTN_STAGE(Ks1, Vs1, kt + 1);
    __builtin_amdgcn_sched_barrier(0);     // pin: issue stages before compute
    ATTN_COMPUTE(Ks0, Vs0, kt);
    __syncthreads();                        // drains stages + publishes

    // tile kt+1 (buffers 1); prefetch kt+2 into buffers 0
    if (kt + 2 < nk) ATTN_STAGE(Ks0, Vs0, kt + 2);
    __builtin_amdgcn_sched_barrier(0);
    ATTN_COMPUTE(Ks1, Vs1, kt + 1);
    __syncthreads();
  }
  if (kt < nk)                              // odd tail: data already in buf 0
    ATTN_COMPUTE(Ks0, Vs0, kt);

#undef ATTN_STAGE
#undef ATTN_COMPUTE

  // ---- epilogue ----
  const float l = l_i + __shfl_xor(l_i, 32);
  const float inv = 1.0f / l;
  const long obase = (long)(b * Sq + q_g) * Eq + head * 64;
#pragma unroll
  for (int nf2 = 0; nf2 < 2; nf2++)
#pragma unroll
    for (int g = 0; g < 4; g++) {
      bf16x4 o;
#pragma unroll
      for (int t = 0; t < 4; t++) o[t] = (__bf16)(oT[nf2][g * 4 + t] * inv);
      *(bf16x4*)(aout + obase + nf2 * 32 + 8 * g + 4 * h) = o;
    }
}

// ---------------- launch ----------------
extern "C" void kernel_launch(void* const* d_in, const int* in_sizes, int n_in,
                              void* d_out, int out_size, void* d_ws, size_t ws_size,
                              hipStream_t stream) {
  const float* x      = (const float*)d_in[0];
  const float* w_qkv  = (const float*)d_in[1];
  const float* w_proj = (const float*)d_in[2];
  const float* b_proj = (const float*)d_in[3];
  float* out = (float*)d_out;

  char* w = (char*)d_ws;
  __bf16* xb     = (__bf16*)w; w += (size_t)Mq * Kq * 2;
  __bf16* wqkvb  = (__bf16*)w; w += (size_t)N1q * Kq * 2;
  __bf16* wprojb = (__bf16*)w; w += (size_t)Eq * Kq * 2;
  __bf16* qkvb   = (__bf16*)w; w += (size_t)Mq * N1q * 2;
  __bf16* vtb    = (__bf16*)w; w += (size_t)Bq * Hq * HDq * Sq * 2;
  __bf16* attnb  = (__bf16*)w;

  cvt_all<<<(NX4 + NW4 + NP4) / 256, 256, 0, stream>>>(x, w_qkv, w_proj, xb, wqkvb, wprojb);

  gemm_bt<0><<<dim3(Mq / 128, N1q / 128), 256, 0, stream>>>(xb, wqkvb, N1q, Kq, qkvb, nullptr, nullptr);

  transv<<<Bq * Hq * (Sq / 64), 256, 0, stream>>>(qkvb, vtb);

  attn_fwd<<<16 * 64, 256, 0, stream>>>(qkvb, vtb, attnb);

  gemm_bt<1><<<dim3(Mq / 128, Eq / 128), 256, 0, stream>>>(attnb, wprojb, Eq, Kq, nullptr, b_proj, out);
}

// Round 5
// 241.410 us; speedup vs baseline: 1.0450x; 1.0450x over previous
//
#include <hip/hip_runtime.h>

// ---- problem constants ----
#define Bq   4
#define Sq   2048
#define Eq   1024
#define Hq   16
#define HDq  64
#define Mq   (Bq*Sq)       // 8192
#define N1q  (3*Eq)        // 3072
#define Kq   Eq            // 1024

#define NX4  (Mq*Kq/4)     // x float4 count        2097152
#define NW4  (N1q*Kq/4)    // w_qkv float4 count     786432
#define NP4  (Eq*Kq/4)     // w_proj float4 count    262144

typedef __bf16 bf16x8 __attribute__((ext_vector_type(8)));
typedef __bf16 bf16x4 __attribute__((ext_vector_type(4)));
typedef float  f32x4  __attribute__((ext_vector_type(4)));
typedef float  f32x16 __attribute__((ext_vector_type(16)));

#define GAS __attribute__((address_space(1)))
#define LAS __attribute__((address_space(3)))

__device__ __forceinline__ void gl2lds16(const void* g, void* l) {
  __builtin_amdgcn_global_load_lds((GAS const void*)g, (LAS void*)l, 16, 0, 0);
}

__device__ __forceinline__ unsigned pack2(float a, float b) {
  union { __bf16 h[2]; unsigned u; } x;
  x.h[0] = (__bf16)a; x.h[1] = (__bf16)b; return x.u;
}

// v_permlane32_swap_b32: a' = [a.lo32, b.lo32], b' = [a.hi32, b.hi32]
// (r3: replaced ds_bpermute __shfl_xor + selects; confirmed win. NOTE the
// 4.46M SQ_LDS_BANK_CONFLICT was NOT from shfl — identical count remains;
// it's the baseline ds_read_b128 fragment pattern, ~10% of CU time.)
__device__ __forceinline__ void perm32swap(unsigned& a, unsigned& b) {
  asm("v_permlane32_swap_b32 %0, %1" : "+v"(a), "+v"(b));
}

// raw v_exp_f32 (args here are always <= -6 or -1e30: no denorm-fixup needed)
__device__ __forceinline__ float fexp2(float x) {
#if __has_builtin(__builtin_amdgcn_exp2f)
  return __builtin_amdgcn_exp2f(x);
#else
  return exp2f(x);
#endif
}

// ---- single fused fp32->bf16 convert for all three inputs --------------
// w_qkv Q-rows (row%192 < 64) get HD^-0.5*log2(e) folded in so attention
// scores exit MFMA already in base-2 domain.
__global__ __launch_bounds__(256) void cvt_all(const float* __restrict__ x,
                                               const float* __restrict__ wqkv,
                                               const float* __restrict__ wproj,
                                               __bf16* __restrict__ xb,
                                               __bf16* __restrict__ wqkvb,
                                               __bf16* __restrict__ wprojb) {
  int i = blockIdx.x * 256 + threadIdx.x;
  const float* src; __bf16* dst; int j; float sc = 1.0f;
  if (i < NX4) {
    src = x; dst = xb; j = i;
  } else if (i < NX4 + NW4) {
    j = i - NX4; src = wqkv; dst = wqkvb;
    const int row = j >> 8;                    // K=1024 -> 256 float4/row
    if ((row % 192) < 64) sc = 0.18033688011112042f;
  } else {
    j = i - NX4 - NW4; src = wproj; dst = wprojb;
  }
  float4 v = ((const float4*)src)[j];
  bf16x4 o = { (__bf16)(v.x * sc), (__bf16)(v.y * sc),
               (__bf16)(v.z * sc), (__bf16)(v.w * sc) };
  ((bf16x4*)dst)[j] = o;
}

// ---------------- GEMM  C = A(MxK) * B(NxK)^T  (both K-major, bf16) ------
// 128x128 tile, BK=64 (two 32-wide kk-halves per sync). LDS 32 KiB
// single-buffered. LDS chunk-XOR swizzle (proven 0 bank conflicts).
template <int MODE>
__global__ __launch_bounds__(256) void gemm_bt(const __bf16* __restrict__ A,
                                               const __bf16* __restrict__ Bw,
                                               int N, int K,
                                               __bf16* __restrict__ cbf,
                                               const float* __restrict__ bias,
                                               float* __restrict__ cf32) {
  __shared__ __align__(16) __bf16 As[128 * 64];   // [kk][128][32], 16 KiB
  __shared__ __align__(16) __bf16 Bs[128 * 64];
  const int tid  = threadIdx.x;
  const int wave = tid >> 6, lane = tid & 63;
  const int quad = lane >> 4, l15 = lane & 15;
  const int wm = wave & 1, wn = wave >> 1;
  const int bm0 = blockIdx.x * 128;
  const int bn0 = blockIdx.y * 128;

  f32x4 acc[4][4] = {};

  const int ar = tid >> 2;
  const int ac = ((tid & 3) ^ ((tid >> 3) & 3)) * 8;   // swizzled global chunk
  const __bf16* Ag0 = A  + (long)(bm0 + ar) * K + ac;
  const __bf16* Bg0 = Bw + (long)(bn0 + ar) * K + ac;
  // region bases: +0 rows 0-63 kk0, +2048 rows 64-127 kk0,
  //               +4096 rows 0-63 kk1, +6144 rows 64-127 kk1
  __bf16* As0 = As + wave * 512;
  __bf16* Bs0 = Bs + wave * 512;

  const int fsw = (l15 >> 1) & 3;                      // fragment-read swizzle
  const int a_rd = (wm * 64 + l15) * 32 + (quad ^ fsw) * 8;
  const int b_rd = (wn * 64 + l15) * 32 + (quad ^ fsw) * 8;

  for (int kc = 0; kc < K; kc += 64) {
    gl2lds16(Ag0 + kc,               As0);
    gl2lds16(Ag0 + 64 * K + kc,      As0 + 2048);
    gl2lds16(Ag0 + kc + 32,          As0 + 4096);
    gl2lds16(Ag0 + 64 * K + kc + 32, As0 + 6144);
    gl2lds16(Bg0 + kc,               Bs0);
    gl2lds16(Bg0 + 64 * K + kc,      Bs0 + 2048);
    gl2lds16(Bg0 + kc + 32,          Bs0 + 4096);
    gl2lds16(Bg0 + 64 * K + kc + 32, Bs0 + 6144);
    __syncthreads();

    bf16x8 af[4], bfr[4];
    // ---- kk0 (K 0..31 of this step) ----
#pragma unroll
    for (int mt = 0; mt < 4; mt++)
      af[mt] = *(const bf16x8*)&As[a_rd + mt * 512];
#pragma unroll
    for (int nt = 0; nt < 4; nt++)
      bfr[nt] = *(const bf16x8*)&Bs[b_rd + nt * 512];
#pragma unroll
    for (int mt = 0; mt < 4; mt++)
#pragma unroll
      for (int nt = 0; nt < 4; nt++)
        acc[mt][nt] = __builtin_amdgcn_mfma_f32_16x16x32_bf16(af[mt], bfr[nt], acc[mt][nt], 0, 0, 0);

    // ---- kk1 (K 32..63 of this step) ----
    bf16x8 af1[4], bfr1[4];
#pragma unroll
    for (int mt = 0; mt < 4; mt++)
      af1[mt] = *(const bf16x8*)&As[4096 + a_rd + mt * 512];
#pragma unroll
    for (int nt = 0; nt < 4; nt++)
      bfr1[nt] = *(const bf16x8*)&Bs[4096 + b_rd + nt * 512];
#pragma unroll
    for (int mt = 0; mt < 4; mt++)
#pragma unroll
      for (int nt = 0; nt < 4; nt++)
        acc[mt][nt] = __builtin_amdgcn_mfma_f32_16x16x32_bf16(af1[mt], bfr1[nt], acc[mt][nt], 0, 0, 0);
    __syncthreads();
  }

#pragma unroll
  for (int nt = 0; nt < 4; nt++) {
    const int n = bn0 + wn * 64 + nt * 16 + l15;
    float bv = 0.f;
    if (MODE == 1) bv = bias[n];
#pragma unroll
    for (int mt = 0; mt < 4; mt++) {
      const int mbase = bm0 + wm * 64 + mt * 16 + quad * 4;
#pragma unroll
      for (int r = 0; r < 4; r++) {
        const long m = mbase + r;
        if (MODE == 0) cbf[m * N + n] = (__bf16)acc[mt][nt][r];
        else           cf32[m * N + n] = acc[mt][nt][r] + bv;
      }
    }
  }
}

// ---------------- V transpose: qkv natural layout -> vt[bh][d][s] --------
__global__ __launch_bounds__(256) void transv(const __bf16* __restrict__ qkv,
                                              __bf16* __restrict__ vt) {
  __shared__ __align__(16) __bf16 T[64 * 64];
  const int tid = threadIdx.x, wave = tid >> 6;
  const int bh = blockIdx.x >> 5, st = blockIdx.x & 31;
  const int b = bh >> 4, h = bh & 15;
  const long gbase = (long)(b * Sq + st * 64 + (tid >> 3)) * N1q + h * 192 + 128 + (tid & 7) * 8;
  gl2lds16(qkv + gbase,                  T + wave * 512);
  gl2lds16(qkv + gbase + (long)32 * N1q, T + 2048 + wave * 512);
  __syncthreads();
  const int d = tid >> 2, s4 = (tid & 3) * 16;
  bf16x8 o0, o1;
#pragma unroll
  for (int j = 0; j < 8; j++) o0[j] = T[(s4 + j) * 64 + d];
#pragma unroll
  for (int j = 0; j < 8; j++) o1[j] = T[(s4 + 8 + j) * 64 + d];
  __bf16* dst = vt + (long)(bh * 64 + d) * Sq + st * 64 + s4;
  *(bf16x8*)dst = o0;
  *(bf16x8*)(dst + 8) = o1;
}

// ---------------- flash attention fwd (causal), transposed-scores --------
// Grid 1024, blockIdx = j*256 + k*64 + bh; qt = 4*j + ((k+j)&3) (Latin
// square: per-CU-slot work uniform). Fixed-max base-2 softmax (scale folded
// into w_qkv cvt; -MB folded into MFMA C-init). Per-nf fusion keeps one
// f32x16 of scores live.
//
// r5: T14 async-STAGE split. Single 32 KiB K/V buffer (r4's 64 KiB dbuf
// halved blocks/CU 4->2 and REGRESSED — revert). Next tile's K/V is loaded
// into 32 VGPRs (8x global_load_dwordx4, issued one full compute-phase
// early) and committed via ds_write_b128 after the post-compute barrier.
// LDS layout/bytes identical to the old global_load_lds path. Exposed
// per-tile stall drops from ~L2-latency to ~8 ds_writes.
// VGPR budget must stay <=128 (4 waves/SIMD -> 4 blocks/CU co-resident).
__global__ __launch_bounds__(256, 2) void attn_fwd(const __bf16* __restrict__ qkv,
                                                   const __bf16* __restrict__ vt,
                                                   __bf16* __restrict__ aout) {
  __shared__ __align__(16) __bf16 Ks[128 * 64];   // [kcol][d], XOR-swizzled
  __shared__ __align__(16) __bf16 Vs[64 * 128];   // [d][kcol], XOR-swizzled

  const int tid = threadIdx.x;
  const int w = tid >> 6, lane = tid & 63;
  const int c = lane & 31, h = lane >> 5;
  const int bi = blockIdx.x;
  const int bh = bi & 63, kk = (bi >> 6) & 3, jr = bi >> 8;
  const int qt = 4 * jr + ((kk + jr) & 3);
  const int b = bh >> 4, head = bh & 15;

  const int krr = lane >> 3, kj = lane & 7;
  const int vrr = lane >> 4, vj = lane & 15;

  const int q_g = qt * 128 + w * 32 + c;

  bf16x8 qf[4];
  const __bf16* qp = qkv + (long)(b * Sq + q_g) * N1q + head * 192 + h * 8;
#pragma unroll
  for (int kc2 = 0; kc2 < 4; kc2++) qf[kc2] = *(const bf16x8*)(qp + kc2 * 16);

  f32x16 oT[2] = {};
  float l_i = 0.f;
  constexpr float MB = 16.0f;   // fixed softmax max (base-2 domain)

  // ---- reg-staging state & addressing (same bytes/addresses as the old
  //      global_load_lds path: swizzled global source, linear LDS dst) ----
  uint4 rk0, rk1, rk2, rk3, rv0, rv1, rv2, rv3;
  const char* gK = (const char*)qkv +
      2 * ((long)(b * Sq + w * 32 + krr) * N1q + head * 192 + 64 + (kj ^ (krr & 7)) * 8);
  const char* gV = (const char*)vt + 2 * ((long)(bh * 64 + w * 16 + vrr) * Sq);
  const int o0 = (vj ^ vrr) * 16, o1 = o0 ^ 64;   // V chunk swizzle, even/odd i
  __bf16* ldsK = Ks + w * 2048 + lane * 8;        // +i*512 per 8-row group
  __bf16* ldsV = Vs + w * 2048 + lane * 8;        // +i*512 per 4-row group

#define LOADKV(kt_) do {                                                      \
    const char* kp_ = gK + (long)(kt_) * (128L * N1q * 2);                    \
    rk0 = *(const uint4*)(kp_);                                               \
    rk1 = *(const uint4*)(kp_ + 1L * 8 * N1q * 2);                            \
    rk2 = *(const uint4*)(kp_ + 2L * 8 * N1q * 2);                            \
    rk3 = *(const uint4*)(kp_ + 3L * 8 * N1q * 2);                            \
    const char* vp_ = gV + (long)(kt_) * 256;                                 \
    rv0 = *(const uint4*)(vp_ + 0 * 16384 + o0);                              \
    rv1 = *(const uint4*)(vp_ + 1 * 16384 + o1);                              \
    rv2 = *(const uint4*)(vp_ + 2 * 16384 + o0);                              \
    rv3 = *(const uint4*)(vp_ + 3 * 16384 + o1);                              \
  } while (0)

#define WRITEKV() do {                                                        \
    union { uint4 u; bf16x8 b; } t_;                                          \
    t_.u = rk0; *(bf16x8*)(ldsK +    0) = t_.b;                               \
    t_.u = rk1; *(bf16x8*)(ldsK +  512) = t_.b;                               \
    t_.u = rk2; *(bf16x8*)(ldsK + 1024) = t_.b;                               \
    t_.u = rk3; *(bf16x8*)(ldsK + 1536) = t_.b;                               \
    t_.u = rv0; *(bf16x8*)(ldsV +    0) = t_.b;                               \
    t_.u = rv1; *(bf16x8*)(ldsV +  512) = t_.b;                               \
    t_.u = rv2; *(bf16x8*)(ldsV + 1024) = t_.b;                               \
    t_.u = rv3; *(bf16x8*)(ldsV + 1536) = t_.b;                               \
  } while (0)

#define ATTN_COMPUTE(kt_) do {                                                \
    const bool diag = ((kt_) == qt);                                          \
    float s_acc = 0.f;                                                        \
    _Pragma("unroll")                                                         \
    for (int nf = 0; nf < 4; nf++) {                                          \
      f32x16 z;                                                               \
      _Pragma("unroll")                                                       \
      for (int r = 0; r < 16; r++) z[r] = -MB;  /* C-init = -MB: no v_sub */  \
      _Pragma("unroll")                                                       \
      for (int kc2 = 0; kc2 < 4; kc2++) {                                     \
        bf16x8 kf = *(const bf16x8*)&Ks[(nf * 32 + c) * 64                    \
                                        + (((kc2 * 2 + h) ^ (c & 7)) * 8)];   \
        z = __builtin_amdgcn_mfma_f32_32x32x16_bf16(kf, qf[kc2], z, 0, 0, 0); \
      }                                                                       \
      if (diag) {                                                             \
        _Pragma("unroll")                                                     \
        for (int r = 0; r < 16; r++) {                                        \
          const int kcol = (kt_) * 128 + nf * 32 + (r & 3) + 8 * (r >> 2)     \
                           + 4 * h;                                           \
          if (kcol > q_g) z[r] = -1e30f;                                      \
        }                                                                     \
      }                                                                       \
      _Pragma("unroll")                                                       \
      for (int r = 0; r < 16; r++) {                                          \
        float p = fexp2(z[r]);                                                \
        z[r] = p; s_acc += p;                                                 \
      }                                                                       \
      _Pragma("unroll")                                                       \
      for (int sub = 0; sub < 2; sub++) {                                     \
        const int kc = nf * 2 + sub, base = 8 * sub;                          \
        unsigned pa0 = pack2(z[base + 0], z[base + 1]);                       \
        unsigned pa1 = pack2(z[base + 2], z[base + 3]);                       \
        unsigned pb0 = pack2(z[base + 4], z[base + 5]);                       \
        unsigned pb1 = pack2(z[base + 6], z[base + 7]);                       \
        perm32swap(pa0, pb0);                                                 \
        perm32swap(pa1, pb1);                                                 \
        union { bf16x8 v; unsigned u[4]; } pf;                                \
        pf.u[0] = pa0; pf.u[1] = pa1; pf.u[2] = pb0; pf.u[3] = pb1;           \
        _Pragma("unroll")                                                     \
        for (int nf2 = 0; nf2 < 2; nf2++) {                                   \
          bf16x8 vf = *(const bf16x8*)&Vs[(nf2 * 32 + c) * 128                \
                                          + (((kc * 2 + h) ^ (c & 7)) * 8)];  \
          oT[nf2] = __builtin_amdgcn_mfma_f32_32x32x16_bf16(vf, pf.v,         \
                                                            oT[nf2], 0, 0, 0);\
        }                                                                     \
      }                                                                       \
    }                                                                         \
    l_i += s_acc;                                                             \
  } while (0)

  const int nk = qt + 1;

  // prologue: tile 0 through regs (vmcnt wait exposed once), issue tile 1
  LOADKV(0);
  WRITEKV();
  __syncthreads();
  if (nk > 1) LOADKV(1);

  for (int kt = 0; kt < nk; kt++) {
    __builtin_amdgcn_sched_barrier(0);   // pin staged loads above compute
    ATTN_COMPUTE(kt);
    __syncthreads();                     // all waves done reading tile kt
    if (kt + 1 < nk) WRITEKV();          // commit kt+1 (loads landed long ago)
    __syncthreads();                     // publish tile kt+1
    if (kt + 2 < nk) LOADKV(kt + 2);     // issue early: hidden under compute
  }

#undef LOADKV
#undef WRITEKV
#undef ATTN_COMPUTE

  // ---- epilogue ----
  const float l = l_i + __shfl_xor(l_i, 32);
  const float inv = 1.0f / l;
  const long obase = (long)(b * Sq + q_g) * Eq + head * 64;
#pragma unroll
  for (int nf2 = 0; nf2 < 2; nf2++)
#pragma unroll
    for (int g = 0; g < 4; g++) {
      bf16x4 o;
#pragma unroll
      for (int t = 0; t < 4; t++) o[t] = (__bf16)(oT[nf2][g * 4 + t] * inv);
      *(bf16x4*)(aout + obase + nf2 * 32 + 8 * g + 4 * h) = o;
    }
}

// ---------------- launch ----------------
extern "C" void kernel_launch(void* const* d_in, const int* in_sizes, int n_in,
                              void* d_out, int out_size, void* d_ws, size_t ws_size,
                              hipStream_t stream) {
  const float* x      = (const float*)d_in[0];
  const float* w_qkv  = (const float*)d_in[1];
  const float* w_proj = (const float*)d_in[2];
  const float* b_proj = (const float*)d_in[3];
  float* out = (float*)d_out;

  char* w = (char*)d_ws;
  __bf16* xb     = (__bf16*)w; w += (size_t)Mq * Kq * 2;
  __bf16* wqkvb  = (__bf16*)w; w += (size_t)N1q * Kq * 2;
  __bf16* wprojb = (__bf16*)w; w += (size_t)Eq * Kq * 2;
  __bf16* qkvb   = (__bf16*)w; w += (size_t)Mq * N1q * 2;
  __bf16* vtb    = (__bf16*)w; w += (size_t)Bq * Hq * HDq * Sq * 2;
  __bf16* attnb  = (__bf16*)w;

  cvt_all<<<(NX4 + NW4 + NP4) / 256, 256, 0, stream>>>(x, w_qkv, w_proj, xb, wqkvb, wprojb);

  gemm_bt<0><<<dim3(Mq / 128, N1q / 128), 256, 0, stream>>>(xb, wqkvb, N1q, Kq, qkvb, nullptr, nullptr);

  transv<<<Bq * Hq * (Sq / 64), 256, 0, stream>>>(qkvb, vtb);

  attn_fwd<<<16 * 64, 256, 0, stream>>>(qkvb, vtb, attnb);

  gemm_bt<1><<<dim3(Mq / 128, Eq / 128), 256, 0, stream>>>(attnb, wprojb, Eq, Kq, nullptr, b_proj, out);
}

// Round 6
// 233.719 us; speedup vs baseline: 1.0794x; 1.0329x over previous
//
#include <hip/hip_runtime.h>

// ---- problem constants ----
#define Bq   4
#define Sq   2048
#define Eq   1024
#define Hq   16
#define HDq  64
#define Mq   (Bq*Sq)       // 8192
#define N1q  (3*Eq)        // 3072
#define Kq   Eq            // 1024

#define NX4  (Mq*Kq/4)     // x float4 count        2097152
#define NW4  (N1q*Kq/4)    // w_qkv float4 count     786432
#define NP4  (Eq*Kq/4)     // w_proj float4 count    262144

typedef __bf16 bf16x8 __attribute__((ext_vector_type(8)));
typedef __bf16 bf16x4 __attribute__((ext_vector_type(4)));
typedef float  f32x4  __attribute__((ext_vector_type(4)));
typedef float  f32x16 __attribute__((ext_vector_type(16)));

#define GAS __attribute__((address_space(1)))
#define LAS __attribute__((address_space(3)))

__device__ __forceinline__ void gl2lds16(const void* g, void* l) {
  __builtin_amdgcn_global_load_lds((GAS const void*)g, (LAS void*)l, 16, 0, 0);
}

__device__ __forceinline__ unsigned pack2(float a, float b) {
  union { __bf16 h[2]; unsigned u; } x;
  x.h[0] = (__bf16)a; x.h[1] = (__bf16)b; return x.u;
}

// v_permlane32_swap_b32: a' = [a.lo32, b.lo32], b' = [a.hi32, b.hi32]
// (r3: replaced ds_bpermute __shfl_xor + selects; confirmed win. NOTE the
// 4.46M SQ_LDS_BANK_CONFLICT was NOT from shfl — identical count remains;
// it's the baseline ds_read_b128 fragment pattern, ~10% of CU time.)
__device__ __forceinline__ void perm32swap(unsigned& a, unsigned& b) {
  asm("v_permlane32_swap_b32 %0, %1" : "+v"(a), "+v"(b));
}

// raw v_exp_f32 (args here are always <= -6 or -1e30: no denorm-fixup needed)
__device__ __forceinline__ float fexp2(float x) {
#if __has_builtin(__builtin_amdgcn_exp2f)
  return __builtin_amdgcn_exp2f(x);
#else
  return exp2f(x);
#endif
}

// ---- single fused fp32->bf16 convert for all three inputs --------------
// w_qkv Q-rows (row%192 < 64) get HD^-0.5*log2(e) folded in so attention
// scores exit MFMA already in base-2 domain.
__global__ __launch_bounds__(256) void cvt_all(const float* __restrict__ x,
                                               const float* __restrict__ wqkv,
                                               const float* __restrict__ wproj,
                                               __bf16* __restrict__ xb,
                                               __bf16* __restrict__ wqkvb,
                                               __bf16* __restrict__ wprojb) {
  int i = blockIdx.x * 256 + threadIdx.x;
  const float* src; __bf16* dst; int j; float sc = 1.0f;
  if (i < NX4) {
    src = x; dst = xb; j = i;
  } else if (i < NX4 + NW4) {
    j = i - NX4; src = wqkv; dst = wqkvb;
    const int row = j >> 8;                    // K=1024 -> 256 float4/row
    if ((row % 192) < 64) sc = 0.18033688011112042f;
  } else {
    j = i - NX4 - NW4; src = wproj; dst = wprojb;
  }
  float4 v = ((const float4*)src)[j];
  bf16x4 o = { (__bf16)(v.x * sc), (__bf16)(v.y * sc),
               (__bf16)(v.z * sc), (__bf16)(v.w * sc) };
  ((bf16x4*)dst)[j] = o;
}

// ---------------- GEMM  C = A(MxK) * B(NxK)^T  (both K-major, bf16) ------
// 128x128 tile, BK=64 (two 32-wide kk-halves per sync). LDS 32 KiB
// single-buffered. LDS chunk-XOR swizzle (proven 0 bank conflicts).
//
// r6 (MODE 0 only): V-columns of the QKV output (n%192 >= 128) are written
// DIRECTLY into the transposed vt[bh][d][s] layout instead of cbf — the
// acc[mt][nt][0..3] quad is 4 consecutive m = 4 consecutive s, i.e. one
// contiguous 8B bf16x4 store. This deletes the separate transv kernel and
// its 12.6 MB qkv V-region round-trip. Values bit-identical ((__bf16)acc
// both paths). The n%192 branch is wave-uniform (16-aligned boundaries).
// qkvb's V-columns are left unwritten (nothing reads them).
template <int MODE>
__global__ __launch_bounds__(256) void gemm_bt(const __bf16* __restrict__ A,
                                               const __bf16* __restrict__ Bw,
                                               int N, int K,
                                               __bf16* __restrict__ cbf,
                                               __bf16* __restrict__ vtout,
                                               const float* __restrict__ bias,
                                               float* __restrict__ cf32) {
  __shared__ __align__(16) __bf16 As[128 * 64];   // [kk][128][32], 16 KiB
  __shared__ __align__(16) __bf16 Bs[128 * 64];
  const int tid  = threadIdx.x;
  const int wave = tid >> 6, lane = tid & 63;
  const int quad = lane >> 4, l15 = lane & 15;
  const int wm = wave & 1, wn = wave >> 1;
  const int bm0 = blockIdx.x * 128;
  const int bn0 = blockIdx.y * 128;

  f32x4 acc[4][4] = {};

  const int ar = tid >> 2;
  const int ac = ((tid & 3) ^ ((tid >> 3) & 3)) * 8;   // swizzled global chunk
  const __bf16* Ag0 = A  + (long)(bm0 + ar) * K + ac;
  const __bf16* Bg0 = Bw + (long)(bn0 + ar) * K + ac;
  // region bases: +0 rows 0-63 kk0, +2048 rows 64-127 kk0,
  //               +4096 rows 0-63 kk1, +6144 rows 64-127 kk1
  __bf16* As0 = As + wave * 512;
  __bf16* Bs0 = Bs + wave * 512;

  const int fsw = (l15 >> 1) & 3;                      // fragment-read swizzle
  const int a_rd = (wm * 64 + l15) * 32 + (quad ^ fsw) * 8;
  const int b_rd = (wn * 64 + l15) * 32 + (quad ^ fsw) * 8;

  for (int kc = 0; kc < K; kc += 64) {
    gl2lds16(Ag0 + kc,               As0);
    gl2lds16(Ag0 + 64 * K + kc,      As0 + 2048);
    gl2lds16(Ag0 + kc + 32,          As0 + 4096);
    gl2lds16(Ag0 + 64 * K + kc + 32, As0 + 6144);
    gl2lds16(Bg0 + kc,               Bs0);
    gl2lds16(Bg0 + 64 * K + kc,      Bs0 + 2048);
    gl2lds16(Bg0 + kc + 32,          Bs0 + 4096);
    gl2lds16(Bg0 + 64 * K + kc + 32, Bs0 + 6144);
    __syncthreads();

    bf16x8 af[4], bfr[4];
    // ---- kk0 (K 0..31 of this step) ----
#pragma unroll
    for (int mt = 0; mt < 4; mt++)
      af[mt] = *(const bf16x8*)&As[a_rd + mt * 512];
#pragma unroll
    for (int nt = 0; nt < 4; nt++)
      bfr[nt] = *(const bf16x8*)&Bs[b_rd + nt * 512];
#pragma unroll
    for (int mt = 0; mt < 4; mt++)
#pragma unroll
      for (int nt = 0; nt < 4; nt++)
        acc[mt][nt] = __builtin_amdgcn_mfma_f32_16x16x32_bf16(af[mt], bfr[nt], acc[mt][nt], 0, 0, 0);

    // ---- kk1 (K 32..63 of this step) ----
    bf16x8 af1[4], bfr1[4];
#pragma unroll
    for (int mt = 0; mt < 4; mt++)
      af1[mt] = *(const bf16x8*)&As[4096 + a_rd + mt * 512];
#pragma unroll
    for (int nt = 0; nt < 4; nt++)
      bfr1[nt] = *(const bf16x8*)&Bs[4096 + b_rd + nt * 512];
#pragma unroll
    for (int mt = 0; mt < 4; mt++)
#pragma unroll
      for (int nt = 0; nt < 4; nt++)
        acc[mt][nt] = __builtin_amdgcn_mfma_f32_16x16x32_bf16(af1[mt], bfr1[nt], acc[mt][nt], 0, 0, 0);
    __syncthreads();
  }

#pragma unroll
  for (int nt = 0; nt < 4; nt++) {
    const int n = bn0 + wn * 64 + nt * 16 + l15;
    float bv = 0.f;
    if (MODE == 1) bv = bias[n];
    const int head = n / 192;                 // magic-mul
    const int c192 = n - head * 192;
#pragma unroll
    for (int mt = 0; mt < 4; mt++) {
      const int mbase = bm0 + wm * 64 + mt * 16 + quad * 4;
      if (MODE == 0) {
        if (c192 >= 128) {
          // V column -> vt[bh][d][s], 4 consecutive s = one 8B store
          const int bh = (mbase >> 11) * 16 + head;     // m/2048 * 16 + head
          const int s0 = mbase & 2047;
          bf16x4 o = { (__bf16)acc[mt][nt][0], (__bf16)acc[mt][nt][1],
                       (__bf16)acc[mt][nt][2], (__bf16)acc[mt][nt][3] };
          *(bf16x4*)&vtout[(long)(bh * 64 + (c192 - 128)) * Sq + s0] = o;
        } else {
#pragma unroll
          for (int r = 0; r < 4; r++)
            cbf[(long)(mbase + r) * N + n] = (__bf16)acc[mt][nt][r];
        }
      } else {
#pragma unroll
        for (int r = 0; r < 4; r++)
          cf32[(long)(mbase + r) * N + n] = acc[mt][nt][r] + bv;
      }
    }
  }
}

// ---------------- flash attention fwd (causal), transposed-scores --------
// Grid 1024, blockIdx = j*256 + k*64 + bh; qt = 4*j + ((k+j)&3) (Latin
// square: per-CU-slot work uniform). Fixed-max base-2 softmax (scale folded
// into w_qkv cvt; -MB folded into MFMA C-init). Per-nf fusion keeps one
// f32x16 of scores live.
//
// r5: T14 async-STAGE split. Single 32 KiB K/V buffer (r4's 64 KiB dbuf
// halved blocks/CU 4->2 and REGRESSED — revert). Next tile's K/V is loaded
// into 32 VGPRs (8x global_load_dwordx4, issued one full compute-phase
// early) and committed via ds_write_b128 after the post-compute barrier.
// LDS layout/bytes identical to the old global_load_lds path. Exposed
// per-tile stall drops from ~L2-latency to ~8 ds_writes.
// VGPR budget must stay <=128 (4 waves/SIMD -> 4 blocks/CU co-resident).
__global__ __launch_bounds__(256, 2) void attn_fwd(const __bf16* __restrict__ qkv,
                                                   const __bf16* __restrict__ vt,
                                                   __bf16* __restrict__ aout) {
  __shared__ __align__(16) __bf16 Ks[128 * 64];   // [kcol][d], XOR-swizzled
  __shared__ __align__(16) __bf16 Vs[64 * 128];   // [d][kcol], XOR-swizzled

  const int tid = threadIdx.x;
  const int w = tid >> 6, lane = tid & 63;
  const int c = lane & 31, h = lane >> 5;
  const int bi = blockIdx.x;
  const int bh = bi & 63, kk = (bi >> 6) & 3, jr = bi >> 8;
  const int qt = 4 * jr + ((kk + jr) & 3);
  const int b = bh >> 4, head = bh & 15;

  const int krr = lane >> 3, kj = lane & 7;
  const int vrr = lane >> 4, vj = lane & 15;

  const int q_g = qt * 128 + w * 32 + c;

  bf16x8 qf[4];
  const __bf16* qp = qkv + (long)(b * Sq + q_g) * N1q + head * 192 + h * 8;
#pragma unroll
  for (int kc2 = 0; kc2 < 4; kc2++) qf[kc2] = *(const bf16x8*)(qp + kc2 * 16);

  f32x16 oT[2] = {};
  float l_i = 0.f;
  constexpr float MB = 16.0f;   // fixed softmax max (base-2 domain)

  // ---- reg-staging state & addressing (same bytes/addresses as the old
  //      global_load_lds path: swizzled global source, linear LDS dst) ----
  uint4 rk0, rk1, rk2, rk3, rv0, rv1, rv2, rv3;
  const char* gK = (const char*)qkv +
      2 * ((long)(b * Sq + w * 32 + krr) * N1q + head * 192 + 64 + (kj ^ (krr & 7)) * 8);
  const char* gV = (const char*)vt + 2 * ((long)(bh * 64 + w * 16 + vrr) * Sq);
  const int o0 = (vj ^ vrr) * 16, o1 = o0 ^ 64;   // V chunk swizzle, even/odd i
  __bf16* ldsK = Ks + w * 2048 + lane * 8;        // +i*512 per 8-row group
  __bf16* ldsV = Vs + w * 2048 + lane * 8;        // +i*512 per 4-row group

#define LOADKV(kt_) do {                                                      \
    const char* kp_ = gK + (long)(kt_) * (128L * N1q * 2);                    \
    rk0 = *(const uint4*)(kp_);                                               \
    rk1 = *(const uint4*)(kp_ + 1L * 8 * N1q * 2);                            \
    rk2 = *(const uint4*)(kp_ + 2L * 8 * N1q * 2);                            \
    rk3 = *(const uint4*)(kp_ + 3L * 8 * N1q * 2);                            \
    const char* vp_ = gV + (long)(kt_) * 256;                                 \
    rv0 = *(const uint4*)(vp_ + 0 * 16384 + o0);                              \
    rv1 = *(const uint4*)(vp_ + 1 * 16384 + o1);                              \
    rv2 = *(const uint4*)(vp_ + 2 * 16384 + o0);                              \
    rv3 = *(const uint4*)(vp_ + 3 * 16384 + o1);                              \
  } while (0)

#define WRITEKV() do {                                                        \
    union { uint4 u; bf16x8 b; } t_;                                          \
    t_.u = rk0; *(bf16x8*)(ldsK +    0) = t_.b;                               \
    t_.u = rk1; *(bf16x8*)(ldsK +  512) = t_.b;                               \
    t_.u = rk2; *(bf16x8*)(ldsK + 1024) = t_.b;                               \
    t_.u = rk3; *(bf16x8*)(ldsK + 1536) = t_.b;                               \
    t_.u = rv0; *(bf16x8*)(ldsV +    0) = t_.b;                               \
    t_.u = rv1; *(bf16x8*)(ldsV +  512) = t_.b;                               \
    t_.u = rv2; *(bf16x8*)(ldsV + 1024) = t_.b;                               \
    t_.u = rv3; *(bf16x8*)(ldsV + 1536) = t_.b;                               \
  } while (0)

#define ATTN_COMPUTE(kt_) do {                                                \
    const bool diag = ((kt_) == qt);                                          \
    float s_acc = 0.f;                                                        \
    _Pragma("unroll")                                                         \
    for (int nf = 0; nf < 4; nf++) {                                          \
      f32x16 z;                                                               \
      _Pragma("unroll")                                                       \
      for (int r = 0; r < 16; r++) z[r] = -MB;  /* C-init = -MB: no v_sub */  \
      _Pragma("unroll")                                                       \
      for (int kc2 = 0; kc2 < 4; kc2++) {                                     \
        bf16x8 kf = *(const bf16x8*)&Ks[(nf * 32 + c) * 64                    \
                                        + (((kc2 * 2 + h) ^ (c & 7)) * 8)];   \
        z = __builtin_amdgcn_mfma_f32_32x32x16_bf16(kf, qf[kc2], z, 0, 0, 0); \
      }                                                                       \
      if (diag) {                                                             \
        _Pragma("unroll")                                                     \
        for (int r = 0; r < 16; r++) {                                        \
          const int kcol = (kt_) * 128 + nf * 32 + (r & 3) + 8 * (r >> 2)     \
                           + 4 * h;                                           \
          if (kcol > q_g) z[r] = -1e30f;                                      \
        }                                                                     \
      }                                                                       \
      _Pragma("unroll")                                                       \
      for (int r = 0; r < 16; r++) {                                          \
        float p = fexp2(z[r]);                                                \
        z[r] = p; s_acc += p;                                                 \
      }                                                                       \
      _Pragma("unroll")                                                       \
      for (int sub = 0; sub < 2; sub++) {                                     \
        const int kc = nf * 2 + sub, base = 8 * sub;                          \
        unsigned pa0 = pack2(z[base + 0], z[base + 1]);                       \
        unsigned pa1 = pack2(z[base + 2], z[base + 3]);                       \
        unsigned pb0 = pack2(z[base + 4], z[base + 5]);                       \
        unsigned pb1 = pack2(z[base + 6], z[base + 7]);                       \
        perm32swap(pa0, pb0);                                                 \
        perm32swap(pa1, pb1);                                                 \
        union { bf16x8 v; unsigned u[4]; } pf;                                \
        pf.u[0] = pa0; pf.u[1] = pa1; pf.u[2] = pb0; pf.u[3] = pb1;           \
        _Pragma("unroll")                                                     \
        for (int nf2 = 0; nf2 < 2; nf2++) {                                   \
          bf16x8 vf = *(const bf16x8*)&Vs[(nf2 * 32 + c) * 128                \
                                          + (((kc * 2 + h) ^ (c & 7)) * 8)];  \
          oT[nf2] = __builtin_amdgcn_mfma_f32_32x32x16_bf16(vf, pf.v,         \
                                                            oT[nf2], 0, 0, 0);\
        }                                                                     \
      }                                                                       \
    }                                                                         \
    l_i += s_acc;                                                             \
  } while (0)

  const int nk = qt + 1;

  // prologue: tile 0 through regs (vmcnt wait exposed once), issue tile 1
  LOADKV(0);
  WRITEKV();
  __syncthreads();
  if (nk > 1) LOADKV(1);

  for (int kt = 0; kt < nk; kt++) {
    __builtin_amdgcn_sched_barrier(0);   // pin staged loads above compute
    ATTN_COMPUTE(kt);
    __syncthreads();                     // all waves done reading tile kt
    if (kt + 1 < nk) WRITEKV();          // commit kt+1 (loads landed long ago)
    __syncthreads();                     // publish tile kt+1
    if (kt + 2 < nk) LOADKV(kt + 2);     // issue early: hidden under compute
  }

#undef LOADKV
#undef WRITEKV
#undef ATTN_COMPUTE

  // ---- epilogue ----
  const float l = l_i + __shfl_xor(l_i, 32);
  const float inv = 1.0f / l;
  const long obase = (long)(b * Sq + q_g) * Eq + head * 64;
#pragma unroll
  for (int nf2 = 0; nf2 < 2; nf2++)
#pragma unroll
    for (int g = 0; g < 4; g++) {
      bf16x4 o;
#pragma unroll
      for (int t = 0; t < 4; t++) o[t] = (__bf16)(oT[nf2][g * 4 + t] * inv);
      *(bf16x4*)(aout + obase + nf2 * 32 + 8 * g + 4 * h) = o;
    }
}

// ---------------- launch ----------------
extern "C" void kernel_launch(void* const* d_in, const int* in_sizes, int n_in,
                              void* d_out, int out_size, void* d_ws, size_t ws_size,
                              hipStream_t stream) {
  const float* x      = (const float*)d_in[0];
  const float* w_qkv  = (const float*)d_in[1];
  const float* w_proj = (const float*)d_in[2];
  const float* b_proj = (const float*)d_in[3];
  float* out = (float*)d_out;

  char* w = (char*)d_ws;
  __bf16* xb     = (__bf16*)w; w += (size_t)Mq * Kq * 2;
  __bf16* wqkvb  = (__bf16*)w; w += (size_t)N1q * Kq * 2;
  __bf16* wprojb = (__bf16*)w; w += (size_t)Eq * Kq * 2;
  __bf16* qkvb   = (__bf16*)w; w += (size_t)Mq * N1q * 2;
  __bf16* vtb    = (__bf16*)w; w += (size_t)Bq * Hq * HDq * Sq * 2;
  __bf16* attnb  = (__bf16*)w;

  cvt_all<<<(NX4 + NW4 + NP4) / 256, 256, 0, stream>>>(x, w_qkv, w_proj, xb, wqkvb, wprojb);

  // QKV GEMM; V-columns written directly into vtb (transv kernel deleted)
  gemm_bt<0><<<dim3(Mq / 128, N1q / 128), 256, 0, stream>>>(xb, wqkvb, N1q, Kq, qkvb, vtb, nullptr, nullptr);

  attn_fwd<<<16 * 64, 256, 0, stream>>>(qkvb, vtb, attnb);

  gemm_bt<1><<<dim3(Mq / 128, Eq / 128), 256, 0, stream>>>(attnb, wprojb, Eq, Kq, nullptr, nullptr, b_proj, out);
}